// Round 13
// baseline (1031.122 us; speedup 1.0000x reference)
//
#include <hip/hip_runtime.h>
#include <hip/hip_bf16.h>
#include <math.h>

#define DEV __device__ __forceinline__

typedef __attribute__((ext_vector_type(8))) short short8;
typedef __attribute__((ext_vector_type(4))) float floatx4;

DEV float b2f_lo(unsigned u) { return __uint_as_float(u << 16); }
DEV float b2f_hi(unsigned u) { return __uint_as_float(u & 0xffff0000u); }

#if __has_builtin(__builtin_amdgcn_exp2f)
DEV float fexp2_(float x) { return __builtin_amdgcn_exp2f(x); }
#else
DEV float fexp2_(float x) { return exp2f(x); }
#endif
#if __has_builtin(__builtin_amdgcn_rcpf)
DEV float frcp_(float x) { return __builtin_amdgcn_rcpf(x); }
#else
DEV float frcp_(float x) { return 1.f / x; }
#endif

// async global->LDS, 16B per lane; LDS dest = uniform base + lane*16;
// GLOBAL source address is per-lane.
DEV void gl2lds16(const void* g, void* l) {
  __builtin_amdgcn_global_load_lds(
      (const __attribute__((address_space(1))) unsigned int*)g,
      (__attribute__((address_space(3))) unsigned int*)l, 16, 0, 0);
}

union U8 { uint4 u; __hip_bfloat16 h[8]; };

// fragment-layout column swizzle (within 64-col groups):
// store of logical col l lands at phys p = swz(l); phys p holds logical invswz(p)
DEV int swz64(int x)    { return (x & ~63) | ((x & 15) << 2) | ((x >> 4) & 3); }
DEV int invswz64(int x) { return (x & ~63) | ((x & 3) << 4) | ((x >> 2) & 15); }

// ------- conv stem v3: LDS-staged rows; write-buffered epilogue --------------
__global__ __launch_bounds__(256) void conv_stem_nhwc(const float* __restrict__ x,
    const float* __restrict__ w, const float* __restrict__ bias,
    __hip_bfloat16* __restrict__ out) {
  __shared__ float sX[3][2052];
  __shared__ float sW[288];
  __shared__ float sB[32];
  const int tid = threadIdx.x;
  const int f = blockIdx.x, n = blockIdx.y;
  const float* xb = x + (size_t)n * 262144;

  for (int i = tid; i < 1536; i += 256) {
    int r = i >> 9, c4 = i & 511;
    int fi = 2 * f - 1 + r;
    float4 v = {0.f, 0.f, 0.f, 0.f};
    if (fi >= 0 && fi < 128) v = *(const float4*)&xb[fi * 2048 + c4 * 4];
    sX[r][1 + c4 * 4 + 0] = v.x;
    sX[r][1 + c4 * 4 + 1] = v.y;
    sX[r][1 + c4 * 4 + 2] = v.z;
    sX[r][1 + c4 * 4 + 3] = v.w;
  }
  if (tid < 3) { sX[tid][0] = 0.f; sX[tid][2049] = 0.f; }
  for (int i = tid; i < 288; i += 256) sW[i] = w[i];
  if (tid < 32) sB[tid] = bias[tid];
  __syncthreads();

  float xv[4][9];
#pragma unroll
  for (int q = 0; q < 4; ++q) {
    int t = tid + q * 256;
#pragma unroll
    for (int r = 0; r < 3; ++r)
#pragma unroll
      for (int dc = 0; dc < 3; ++dc)
        xv[q][r * 3 + dc] = sX[r][2 * t + dc];
  }

  U8 ores[4][4];  // [ocq][q]
#pragma unroll
  for (int ocq = 0; ocq < 4; ++ocq) {
#pragma unroll
    for (int oo = 0; oo < 8; ++oo) {
      float w9[9];
#pragma unroll
      for (int qq = 0; qq < 9; ++qq) w9[qq] = sW[(ocq * 8 + oo) * 9 + qq];
      float b0 = sB[ocq * 8 + oo];
#pragma unroll
      for (int q = 0; q < 4; ++q) {
        float acc = b0;
#pragma unroll
        for (int qq = 0; qq < 9; ++qq) acc = fmaf(w9[qq], xv[q][qq], acc);
        ores[ocq][q].h[oo] = __float2bfloat16(acc);
      }
    }
  }

#pragma unroll
  for (int q = 0; q < 4; ++q) {
    int t = tid + q * 256;
    uint4* dst = (uint4*)&out[(((size_t)n * 64 + f) * 1024 + t) * 32];
    dst[0] = ores[0][q].u;
    dst[1] = ores[1][q].u;
    dst[2] = ores[2][q].u;
    dst[3] = ores[3][q].u;
  }
}

// ----- batched weight swizzle: 6 conv layers -> [buf][tap][oc][ic] bf16 ------
__global__ __launch_bounds__(256) void wtap_conv6(const float* __restrict__ w1,
    const float* __restrict__ w2, __hip_bfloat16* __restrict__ out) {
  int i = blockIdx.x * 256 + threadIdx.x;        // 0..55295
  if (i < 55296) {
    int b = i / 9216, r = i - b * 9216;
    int layer = b >> 1, which = b & 1;
    const float* src = (which ? w2 : w1) + layer * 9216;
    int tap = r >> 10, oc = (r >> 5) & 31, ic = r & 31;
    out[b * 9216 + r] = __float2bfloat16(src[(oc * 32 + ic) * 9 + tap]);
  }
}

// ------ FUSED residual block: h2 = relu(bn2(conv2(relu(bn1(conv1(h))))) + h) -
// Block: 4 f-rows x 64 t of output. Stage 8x68x32 input halo tile (sIn);
// conv1 -> 6x66 h1 tile in sH1 (masked zero outside global range, since
// conv-of-padding != 0); conv2 reads sH1 (verbatim old kernel); residual
// served from sIn (no global re-read); sH1 reused as output staging.
__global__ __launch_bounds__(256) void conv_res_fused(
    const __hip_bfloat16* __restrict__ Hin,
    const __hip_bfloat16* __restrict__ wt1, const __hip_bfloat16* __restrict__ wt2,
    const float* __restrict__ cb1, const float* __restrict__ bg1,
    const float* __restrict__ bb1, const float* __restrict__ bm1,
    const float* __restrict__ bv1,
    const float* __restrict__ cb2, const float* __restrict__ bg2,
    const float* __restrict__ bb2, const float* __restrict__ bm2,
    const float* __restrict__ bv2,
    __hip_bfloat16* __restrict__ Hout) {
  __shared__ __hip_bfloat16 sIn[8 * 68 * 40];   // 43520 B
  __shared__ __hip_bfloat16 sH1[6 * 66 * 40];   // 31680 B (reused as sOut)
  const int tid = threadIdx.x;
  const int tb = blockIdx.x, fb = blockIdx.y, n = blockIdx.z;
  const int t0 = tb * 64, f0 = fb * 4;
  const __hip_bfloat16* Hb = Hin + (size_t)n * 2097152;

  // stage 8 f-rows x 68 t x 32 ic (2-wide halo, zero-padded)
  for (int c = tid; c < 2176; c += 256) {
    int rr = c / 272;
    int r2 = c - rr * 272;
    int p = r2 >> 2, icq = r2 & 3;
    int fi = f0 - 2 + rr;
    int tg = t0 + p - 2;
    uint4 v = {0, 0, 0, 0};
    if (fi >= 0 && fi < 64 && tg >= 0 && tg < 1024)
      v = *(const uint4*)&Hb[((size_t)fi * 1024 + tg) * 32 + icq * 8];
    *(uint4*)&sIn[(rr * 68 + p) * 40 + icq * 8] = v;
  }

  const int lane = tid & 63, wave = tid >> 6;
  const int fr = lane & 15, fq = lane >> 4;

  // conv1 weights + bn1 folding
  short8 bfrag[9][2];
#pragma unroll
  for (int tap = 0; tap < 9; ++tap)
#pragma unroll
    for (int j = 0; j < 2; ++j)
      bfrag[tap][j] = *(const short8*)&wt1[(tap * 32 + j * 16 + fr) * 32 + fq * 8];
  float sc10 = bg1[fr] * rsqrtf(bv1[fr] + 1e-5f);
  float sh10 = (cb1[fr] - bm1[fr]) * sc10 + bb1[fr];
  float sc11 = bg1[fr + 16] * rsqrtf(bv1[fr + 16] + 1e-5f);
  float sh11 = (cb1[fr + 16] - bm1[fr + 16]) * sc11 + bb1[fr + 16];

  __syncthreads();  // sIn ready

  // conv1: 30 units = 6 h1-rows x 5 t-groups (bases cover tl 0..65; the
  // 50..63 overlap is computed twice with identical values — benign).
  {
    const int tgbase5[5] = {0, 16, 32, 48, 50};
    for (int u = wave; u < 30; u += 4) {
      int frow = u / 5;
      int tg = u - frow * 5;
      int tb0 = tgbase5[tg];
      floatx4 a0 = (floatx4){0.f, 0.f, 0.f, 0.f};
      floatx4 a1 = (floatx4){0.f, 0.f, 0.f, 0.f};
#pragma unroll
      for (int df = 0; df < 3; ++df)
#pragma unroll
        for (int dc = 0; dc < 3; ++dc) {
          short8 af = *(const short8*)
              &sIn[((frow + df) * 68 + tb0 + fr + dc) * 40 + fq * 8];
          a0 = __builtin_amdgcn_mfma_f32_16x16x32_bf16(
              af, bfrag[df * 3 + dc][0], a0, 0, 0, 0);
          a1 = __builtin_amdgcn_mfma_f32_16x16x32_bf16(
              af, bfrag[df * 3 + dc][1], a1, 0, 0, 0);
        }
      int gf = f0 - 1 + frow;
      bool fv = (gf >= 0) && (gf < 64);
      __hip_bfloat16 z = __float2bfloat16(0.f);
#pragma unroll
      for (int reg = 0; reg < 4; ++reg) {
        int tl = tb0 + fq * 4 + reg;
        int gt = t0 - 1 + tl;
        bool v = fv && (gt >= 0) && (gt < 1024);
        __hip_bfloat16 h0 = __float2bfloat16(a0[reg] * sc10 + sh10);
        __hip_bfloat16 h1 = __float2bfloat16(a1[reg] * sc11 + sh11);
        h0 = __float2bfloat16(fmaxf(__bfloat162float(h0), 0.f));
        h1 = __float2bfloat16(fmaxf(__bfloat162float(h1), 0.f));
        sH1[(frow * 66 + tl) * 40 + fr] = v ? h0 : z;
        sH1[(frow * 66 + tl) * 40 + 16 + fr] = v ? h1 : z;
      }
    }
  }

  // conv2 weights + bn2 folding (reuse bfrag registers)
#pragma unroll
  for (int tap = 0; tap < 9; ++tap)
#pragma unroll
    for (int j = 0; j < 2; ++j)
      bfrag[tap][j] = *(const short8*)&wt2[(tap * 32 + j * 16 + fr) * 32 + fq * 8];
  float sc20 = bg2[fr] * rsqrtf(bv2[fr] + 1e-5f);
  float sh20 = (cb2[fr] - bm2[fr]) * sc20 + bb2[fr];
  float sc21 = bg2[fr + 16] * rsqrtf(bv2[fr + 16] + 1e-5f);
  float sh21 = (cb2[fr + 16] - bm2[fr + 16]) * sc21 + bb2[fr + 16];

  __syncthreads();  // sH1 ready

  const int tw = wave * 16;
  floatx4 acc[4][2];
#pragma unroll
  for (int fp = 0; fp < 4; ++fp)
#pragma unroll
    for (int j = 0; j < 2; ++j) acc[fp][j] = (floatx4){0.f, 0.f, 0.f, 0.f};

#pragma unroll
  for (int fp = 0; fp < 4; ++fp) {
    int pbase = tw + fr;
#pragma unroll
    for (int df = 0; df < 3; ++df)
#pragma unroll
      for (int dc = 0; dc < 3; ++dc) {
        short8 af =
            *(const short8*)&sH1[((fp + df) * 66 + pbase + dc) * 40 + fq * 8];
        acc[fp][0] = __builtin_amdgcn_mfma_f32_16x16x32_bf16(
            af, bfrag[df * 3 + dc][0], acc[fp][0], 0, 0, 0);
        acc[fp][1] = __builtin_amdgcn_mfma_f32_16x16x32_bf16(
            af, bfrag[df * 3 + dc][1], acc[fp][1], 0, 0, 0);
      }
  }

  __syncthreads();  // all sH1 reads done; reuse as sOut
#pragma unroll
  for (int fp = 0; fp < 4; ++fp)
#pragma unroll
    for (int j = 0; j < 2; ++j) {
      float sc = j ? sc21 : sc20, sh = j ? sh21 : sh20;
#pragma unroll
      for (int reg = 0; reg < 4; ++reg) {
        int t_l = tw + fq * 4 + reg;
        sH1[(fp * 64 + t_l) * 40 + j * 16 + fr] =
            __float2bfloat16(acc[fp][j][reg] * sc + sh);
      }
    }
  __syncthreads();

  // final: y + residual (from sIn) -> relu -> global
  for (int c = tid; c < 1024; c += 256) {
    int fp = c >> 8, rem = c & 255;
    int t_l = rem >> 2, icq = rem & 3;
    U8 y;
    y.u = *(uint4*)&sH1[(fp * 64 + t_l) * 40 + icq * 8];
    U8 r;
    r.u = *(uint4*)&sIn[((fp + 2) * 68 + t_l + 2) * 40 + icq * 8];
    U8 o;
#pragma unroll
    for (int i = 0; i < 8; ++i)
      o.h[i] = __float2bfloat16(
          fmaxf(__bfloat162float(y.h[i]) + __bfloat162float(r.h[i]), 0.f));
    size_t addr = (((size_t)n * 64 + f0 + fp) * 1024 + t0 + t_l) * 32 + icq * 8;
    *(uint4*)&Hout[addr] = o.u;
  }
}

// ------ LN over NHWC row (t,n): F=2048, k-order k' = f*32+ic, bf16 out -------
__global__ __launch_bounds__(256) void ln_nhwc(const __hip_bfloat16* __restrict__ H,
    const float* __restrict__ g, const float* __restrict__ b,
    __hip_bfloat16* __restrict__ xn) {
  int r = blockIdx.x;
  int t = r >> 4, n = r & 15;
  int tid = threadIdx.x;
  int f = tid >> 2, icq = tid & 3;
  U8 v;
  v.u = *(const uint4*)&H[(((size_t)n * 64 + f) * 1024 + t) * 32 + icq * 8];
  float xv[8];
  float sum = 0.f, ss = 0.f;
#pragma unroll
  for (int i = 0; i < 8; ++i) {
    xv[i] = __bfloat162float(v.h[i]);
    sum += xv[i];
    ss += xv[i] * xv[i];
  }
#pragma unroll
  for (int off = 32; off > 0; off >>= 1) {
    sum += __shfl_down(sum, off);
    ss  += __shfl_down(ss, off);
  }
  __shared__ float red[8];
  int lane = tid & 63, wave = tid >> 6;
  if (lane == 0) { red[wave] = sum; red[4 + wave] = ss; }
  __syncthreads();
  sum = red[0] + red[1] + red[2] + red[3];
  ss  = red[4] + red[5] + red[6] + red[7];
  float mean = sum * (1.f / 2048.f);
  float var = ss * (1.f / 2048.f) - mean * mean;
  float inv = rsqrtf(var + 1e-5f);
  U8 o;
#pragma unroll
  for (int i = 0; i < 8; ++i) {
    int cf = (icq * 8 + i) * 64 + f;
    o.h[i] = __float2bfloat16((xv[i] - mean) * inv * g[cf] + b[cf]);
  }
  *(uint4*)&xn[(size_t)r * 2048 + tid * 8] = o.u;
}

// -- wproj0 permuted transpose: Wp0t[p][k'=f*32+ic] = wproj0[ic*64+f][p] bf16 --
__global__ __launch_bounds__(256) void wt_perm0(const float* __restrict__ in,
    __hip_bfloat16* __restrict__ out) {
  int i = blockIdx.x * 256 + threadIdx.x;
  int p = i >> 11, kp = i & 2047;
  int ic = kp & 31, f = kp >> 5;
  out[i] = __float2bfloat16(in[(ic * 64 + f) * 256 + p]);
}

// ------- weight convert+transpose (batched over z): (K x N) -> (N x K) bf16 --
__global__ __launch_bounds__(256) void wt_bf16(const float* __restrict__ in,
    __hip_bfloat16* __restrict__ out, int K, int N, int inStride, int outStride) {
  __shared__ float tile[32][33];
  int x = threadIdx.x, y0 = threadIdx.y;
  int bn = blockIdx.x * 32;
  int bk = blockIdx.y * 32;
  const float* src = in + (size_t)blockIdx.z * inStride;
  __hip_bfloat16* dst = out + (size_t)blockIdx.z * outStride;
#pragma unroll
  for (int i = 0; i < 4; ++i) {
    int yy = y0 + i * 8;
    tile[yy][x] = src[(size_t)(bk + yy) * N + bn + x];
  }
  __syncthreads();
#pragma unroll
  for (int i = 0; i < 4; ++i) {
    int yy = y0 + i * 8;
    dst[(size_t)(bn + yy) * K + bk + x] = __float2bfloat16(tile[x][yy]);
  }
}

// ---- expansion weight prep (batched): w (256 x korig*1024) fp32 ->
// ---- PHYSICAL U layout (after the GEMM's fragment-swizzled store) matches
// ---- the historical layout, ch = d*512+j:
// ----   korig==4: plane01 ch*2+{0,1} (a0,a1), plane23 2048+ch*2+{0,1} (a2,rx)
// ----   korig==3: plane01 ch*2+{0,1}, a2 plane 2048+ch
// ---- Bt row index = invswz64(physical col); K-cols swizzled to match the
// ---- proj GEMM's swizzled tmp output. -------------------------------------
__global__ void wexp_prep(const float* __restrict__ in,
    __hip_bfloat16* __restrict__ out, int korig, int inStride, int outStride) {
  __shared__ float tile[32][33];
  int jt = blockIdx.x;
  int ckt = blockIdx.y;
  int z = blockIdx.z;
  int layer = z >> 3, dk = z & 7;
  int d = dk >> 2, k = dk & 3;
  if (k >= korig) return;
  const float* src = in + (size_t)layer * inStride;
  __hip_bfloat16* dst = out + (size_t)layer * outStride;
  int x = threadIdx.x, y0 = threadIdx.y;
#pragma unroll
  for (int i = 0; i < 4; ++i) {
    int yy = y0 + i * 8;
    tile[yy][x] = src[(size_t)(ckt * 32 + yy) * (korig * 1024) +
                      (d * korig + k) * 512 + jt * 32 + x];
  }
  __syncthreads();
#pragma unroll
  for (int i = 0; i < 4; ++i) {
    int yy = y0 + i * 8;
    int ch = d * 512 + jt * 32 + yy;
    int rOld;
    if (korig == 4)
      rOld = (k < 2) ? (ch * 2 + k) : (2048 + ch * 2 + (k - 2));
    else
      rOld = (k < 2) ? (ch * 2 + k) : (2048 + ch);
    int rNew = invswz64(rOld);
    int ckp = swz64(ckt * 32 + x);
    dst[(size_t)rNew * 256 + ckp] = __float2bfloat16(tile[x][yy]);
  }
}

// ---- per-column scale/bias tables (physical col) ---------------------------
__global__ __launch_bounds__(256) void colsb_prep(const float* __restrict__ bias0,
    const float* __restrict__ bias3, float2* __restrict__ out) {
  int i = blockIdx.x * 256 + threadIdx.x;
  if (i >= 13312) return;
  const float NL2E = -1.44269504f;
  float s = 1.f, bb = 0.f;
  if (i < 4096) {
    int col = i;
    if (col < 2048) {
      int ch = col >> 1, e = col & 1;
      int d = ch >> 9, jj = ch & 511;
      if (e) { s = NL2E; bb = NL2E * bias0[d * 1024 + jj]; }
    } else {
      int cc = col - 2048, ch = cc >> 1, e = cc & 1;
      int d = ch >> 9, jj = ch & 511;
      if (!e) { s = NL2E; bb = NL2E * bias0[d * 1024 + 512 + jj]; }
    }
  } else {
    int rem = i - 4096;
    int layer = rem / 3072, col = rem - layer * 3072;
    const float* bsrc = bias3 + layer * 2048;
    if (col < 2048) {
      int ch = col >> 1, e = col & 1;
      int d = ch >> 9, jj = ch & 511;
      if (e) { s = NL2E; bb = NL2E * bsrc[d * 1024 + jj]; }
    } else {
      int ch = col - 2048;
      int d = ch >> 9, jj = ch & 511;
      s = NL2E; bb = NL2E * bsrc[d * 1024 + 512 + jj];
    }
  }
  out[i] = make_float2(s, bb);
}

// ---- cls_w (1024x30) fp32 -> Wct (32x1024) bf16, rows >=30 zero -------------
__global__ __launch_bounds__(256) void wct_prep(const float* __restrict__ in,
    __hip_bfloat16* __restrict__ out) {
  int i = blockIdx.x * 256 + threadIdx.x;
  int nn = i >> 10, kk = i & 1023;
  out[i] = __float2bfloat16(nn < 30 ? in[kk * 30 + nn] : 0.f);
}

// -------- bf16 MFMA GEMM v2: BK=64 double-buffered, counted-vmcnt ------------
__global__ __launch_bounds__(256) void gemm_bf16(const __hip_bfloat16* __restrict__ A,
    const __hip_bfloat16* __restrict__ Bt, __hip_bfloat16* __restrict__ C,
    const float2* __restrict__ csb, int M, int N, int K) {
  __shared__ __hip_bfloat16 As[2][128 * 64];
  __shared__ __hip_bfloat16 Bs[2][128 * 64];
  const int tid = threadIdx.x;
  const int gx = gridDim.x;
  const int nwg = gx * gridDim.y;
  const int bid = blockIdx.y * gx + blockIdx.x;
  const int wgid = (bid & 7) * (nwg >> 3) + (bid >> 3);
  const int m0 = (wgid / gx) * 128, n0 = (wgid % gx) * 128;
  const int lane = tid & 63, wave = tid >> 6;
  const int wm = wave & 1, wn = wave >> 1;
  const int fr = lane & 15, fq = lane >> 4;
  const int frx = fr & 7;

  const int srow8 = lane >> 3;
  const int lslot = (lane & 7) ^ srow8;
  const __hip_bfloat16* gaS = &A[(size_t)(m0 + wave * 32 + srow8) * K + lslot * 8];
  const __hip_bfloat16* gbS = &Bt[(size_t)(n0 + wave * 32 + srow8) * K + lslot * 8];

  floatx4 acc[4][4];
#pragma unroll
  for (int i = 0; i < 4; ++i)
#pragma unroll
    for (int j = 0; j < 4; ++j)
      acc[i][j] = (floatx4){0.f, 0.f, 0.f, 0.f};

#define STAGE(BUF, kk)                                                    \
  {                                                                       \
    _Pragma("unroll") for (int i = 0; i < 4; ++i) {                       \
      gl2lds16(gaS + (size_t)i * 8 * K + (kk),                            \
               &As[BUF][(wave * 32 + i * 8) * 64]);                       \
      gl2lds16(gbS + (size_t)i * 8 * K + (kk),                            \
               &Bs[BUF][(wave * 32 + i * 8) * 64]);                       \
    }                                                                     \
  }
#define COMPUTE(BUF)                                                      \
  {                                                                       \
    _Pragma("unroll") for (int s = 0; s < 2; ++s) {                       \
      const int sl = ((s * 4 + fq) ^ frx) * 8;                            \
      short8 af[4], bf_[4];                                               \
      _Pragma("unroll") for (int i = 0; i < 4; ++i) {                     \
        af[i]  = *(const short8*)&As[BUF][(wm * 64 + i * 16 + fr) * 64 + sl]; \
        bf_[i] = *(const short8*)&Bs[BUF][(wn * 64 + i * 16 + fr) * 64 + sl]; \
      }                                                                   \
      _Pragma("unroll") for (int i = 0; i < 4; ++i)                       \
        _Pragma("unroll") for (int j = 0; j < 4; ++j)                     \
          acc[i][j] = __builtin_amdgcn_mfma_f32_16x16x32_bf16(            \
              af[i], bf_[j], acc[i][j], 0, 0, 0);                         \
    }                                                                     \
  }
#define CFENCE asm volatile("" ::: "memory")

  STAGE(0, 0);
  for (int k0 = 0; k0 < K; k0 += 128) {
    STAGE(1, k0 + 64);
    asm volatile("s_waitcnt vmcnt(8)" ::: "memory");
    __builtin_amdgcn_s_barrier();
    COMPUTE(0);
    CFENCE;
    __builtin_amdgcn_s_barrier();
    if (k0 + 128 < K) {
      STAGE(0, k0 + 128);
      asm volatile("s_waitcnt vmcnt(8)" ::: "memory");
    } else {
      asm volatile("s_waitcnt vmcnt(0)" ::: "memory");
    }
    __builtin_amdgcn_s_barrier();
    COMPUTE(1);
    CFENCE;
    __builtin_amdgcn_s_barrier();
  }
#undef STAGE
#undef COMPUTE
#undef CFENCE

  const int p0 = n0 + wn * 64 + fr * 4;
  float s0 = 1.f, s1 = 1.f, s2 = 1.f, s3 = 1.f;
  float c0 = 0.f, c1 = 0.f, c2v = 0.f, c3 = 0.f;
  if (csb) {
    float2 t0 = csb[p0], t1 = csb[p0 + 1], t2 = csb[p0 + 2], t3 = csb[p0 + 3];
    s0 = t0.x; c0 = t0.y; s1 = t1.x; c1 = t1.y;
    s2 = t2.x; c2v = t2.y; s3 = t3.x; c3 = t3.y;
  }
#pragma unroll
  for (int i = 0; i < 4; ++i)
#pragma unroll
    for (int reg = 0; reg < 4; ++reg) {
      int row = m0 + wm * 64 + i * 16 + fq * 4 + reg;
      union { uint2 u; __hip_bfloat16 h[4]; } o;
      o.h[0] = __float2bfloat16(fmaf(acc[i][0][reg], s0, c0));
      o.h[1] = __float2bfloat16(fmaf(acc[i][1][reg], s1, c1));
      o.h[2] = __float2bfloat16(fmaf(acc[i][2][reg], s2, c2v));
      o.h[3] = __float2bfloat16(fmaf(acc[i][3][reg], s3, c3));
      *(uint2*)&C[(size_t)row * N + p0] = o.u;
    }
}

// ------- skinny classifier GEMM: out[n][t][30] = xnc(16384x1024) @ Wct^T -----
__global__ __launch_bounds__(256) void cls_gemm(const __hip_bfloat16* __restrict__ A,
    const __hip_bfloat16* __restrict__ Wct, float* __restrict__ out) {
  const int tid = threadIdx.x;
  const int lane = tid & 63, wave = tid >> 6;
  const int fr = lane & 15, fq = lane >> 4;
  const int m0 = (blockIdx.x * 4 + wave) * 16;
  floatx4 acc[2];
  acc[0] = (floatx4){0.f, 0.f, 0.f, 0.f};
  acc[1] = (floatx4){0.f, 0.f, 0.f, 0.f};
#pragma unroll 4
  for (int k0 = 0; k0 < 1024; k0 += 32) {
    short8 af = *(const short8*)&A[(size_t)(m0 + fr) * 1024 + k0 + fq * 8];
    short8 b0 = *(const short8*)&Wct[(size_t)fr * 1024 + k0 + fq * 8];
    short8 b1 = *(const short8*)&Wct[(size_t)(16 + fr) * 1024 + k0 + fq * 8];
    acc[0] = __builtin_amdgcn_mfma_f32_16x16x32_bf16(af, b0, acc[0], 0, 0, 0);
    acc[1] = __builtin_amdgcn_mfma_f32_16x16x32_bf16(af, b1, acc[1], 0, 0, 0);
  }
#pragma unroll
  for (int j = 0; j < 2; ++j) {
    int col = j * 16 + fr;
    if (col < 30) {
#pragma unroll
      for (int reg = 0; reg < 4; ++reg) {
        int row = m0 + fq * 4 + reg;
        int t = row >> 4, n = row & 15;
        out[(size_t)n * 30720 + t * 30 + col] = acc[j][reg];
      }
    }
  }
}

// ---------- SRU c-chain (pass 1), producer/consumer LDS pipeline -------------
// (round-12 verified version)
template <int ROWB>
__global__ __launch_bounds__(128) void scan_c(const __hip_bfloat16* __restrict__ U,
    const float* __restrict__ vc, __hip_bfloat16* __restrict__ c2out) {
  __shared__ uint slab[16 * 1024];   // 16 slots x 4 KB
  const int b = blockIdx.x;
  const int lane = threadIdx.x & 63;
  const int wave = threadIdx.x >> 6;
  const int jb = (b * 64) & 511;          // block's j base
  const int n = (b >> 3) & 15;
  const int d = b >> 7;
  const float NL2E = -1.44269504f;

  const ptrdiff_t US = (ptrdiff_t)16 * ROWB;        // per-t-step byte stride
  const char* stripe0 = (const char*)U + (size_t)n * ROWB + (size_t)(d * 512 + jb) * 4;
  const char* baseDir = d ? stripe0 + 1023 * US : stripe0;
  const ptrdiff_t stepStride = d ? -US : US;

  if (wave == 1) {
    // ---- producer ----
    const int D = 12;
    const int sgrp = lane >> 4;             // step-in-group 0..3
    const int chunk = lane & 15;            // 16B chunk within 256B stripe
#define ISSUE4(BB)                                                        \
    {                                                                     \
      int slot = (BB) & 15;                                               \
      _Pragma("unroll") for (int i = 0; i < 4; ++i) {                     \
        int s = (BB) * 16 + i * 4 + sgrp;                                 \
        const char* src = baseDir + (ptrdiff_t)s * stepStride + chunk * 16; \
        gl2lds16(src, (char*)slab + slot * 4096 + i * 1024);              \
      }                                                                   \
    }
    for (int bb = 0; bb < D; ++bb) ISSUE4(bb);
    for (int bb = 0; bb < 64; ++bb) {
      if (bb + D < 64) {
        ISSUE4(bb + D);
        asm volatile("s_waitcnt vmcnt(48)" ::: "memory");
      } else {
        asm volatile("s_waitcnt vmcnt(0)" ::: "memory");
      }
      __builtin_amdgcn_s_barrier();
    }
#undef ISSUE4
  } else {
    // ---- consumer ----
    const int j = jb + lane;
    float vf2 = NL2E * vc[d * 1024 + j];
    char* Ob = (char*)c2out + (size_t)n * 2048 + (size_t)(d * 512 + j) * 2;
    const int OS = d ? -32768 : 32768;
    int ooff = d ? 1023 * 32768 : 0;
    float c = 0.f;
    for (int bb = 0; bb < 64; ++bb) {
      __builtin_amdgcn_s_barrier();
      asm volatile("" ::: "memory");
      const uint* slot = slab + (bb & 15) * 1024;
#pragma unroll
      for (int ss = 0; ss < 16; ++ss) {
        uint u = slot[ss * 64 + lane];
        float a0 = b2f_lo(u), a1p = b2f_hi(u);
        float f = frcp_(1.f + fexp2_(fmaf(vf2, c, a1p)));
        c = fmaf(f, c - a0, a0);
        *(__hip_bfloat16*)(Ob + ooff) = __float2bfloat16(c);
        ooff += OS;
      }
    }
  }
}

// ---------- fused y = r*c2 + (1-r)*rx  +  LayerNorm over 1024 (pass 2) -------
template <int K4>
__global__ __launch_bounds__(256) void yln(const __hip_bfloat16* __restrict__ c2buf,
    const __hip_bfloat16* __restrict__ U, const __hip_bfloat16* __restrict__ xn,
    const float* __restrict__ vc, const float* __restrict__ g,
    const float* __restrict__ b, __hip_bfloat16* __restrict__ outx) {
  int r = blockIdx.x;
  int tid = threadIdx.x;
  int ch0 = tid * 4;
  const float NL2E = -1.44269504f;

  union { ushort4 u; __hip_bfloat16 h[4]; } cv;
  cv.u = *(const ushort4*)&c2buf[(size_t)r * 1024 + ch0];
  float a2p[4], rx[4];
  if (K4) {
    uint4 pr = *(const uint4*)((const char*)U + (size_t)r * 8192 + 4096 + tid * 16);
    uint pp[4] = {pr.x, pr.y, pr.z, pr.w};
#pragma unroll
    for (int i = 0; i < 4; ++i) { a2p[i] = b2f_lo(pp[i]); rx[i] = b2f_hi(pp[i]); }
  } else {
    union { ushort4 u; __hip_bfloat16 h[4]; } av, xv;
    av.u = *(const ushort4*)((const char*)U + (size_t)r * 6144 + 4096 + tid * 8);
    xv.u = *(const ushort4*)&xn[(size_t)r * 1024 + ch0];
#pragma unroll
    for (int i = 0; i < 4; ++i) {
      a2p[i] = __bfloat162float(av.h[i]);
      rx[i]  = __bfloat162float(xv.h[i]);
    }
  }

  int d = ch0 >> 9, j0 = ch0 & 511;
  float y[4], sum = 0.f, ss = 0.f;
#pragma unroll
  for (int i = 0; i < 4; ++i) {
    float vr2 = NL2E * vc[d * 1024 + 512 + j0 + i];
    float cc = __bfloat162float(cv.h[i]);
    float rr = frcp_(1.f + fexp2_(fmaf(vr2, cc, a2p[i])));
    y[i] = fmaf(rr, cc - rx[i], rx[i]);
    sum += y[i];
    ss += y[i] * y[i];
  }
#pragma unroll
  for (int off = 32; off > 0; off >>= 1) {
    sum += __shfl_down(sum, off);
    ss  += __shfl_down(ss, off);
  }
  __shared__ float red[8];
  int lane = tid & 63, wave = tid >> 6;
  if (lane == 0) { red[wave] = sum; red[4 + wave] = ss; }
  __syncthreads();
  sum = red[0] + red[1] + red[2] + red[3];
  ss  = red[4] + red[5] + red[6] + red[7];
  float mean = sum * (1.f / 1024.f);
  float var = ss * (1.f / 1024.f) - mean * mean;
  float inv = rsqrtf(var + 1e-5f);
  float4 gv = *(const float4*)&g[ch0];
  float4 bv = *(const float4*)&b[ch0];
  float gg[4] = {gv.x, gv.y, gv.z, gv.w};
  float bb[4] = {bv.x, bv.y, bv.z, bv.w};
  union { ushort4 u; __hip_bfloat16 h[4]; } o;
#pragma unroll
  for (int i = 0; i < 4; ++i)
    o.h[i] = __float2bfloat16((y[i] - mean) * inv * gg[i] + bb[i]);
  *(ushort4*)&outx[(size_t)r * 1024 + ch0] = o.u;
}

extern "C" void kernel_launch(void* const* d_in, const int* in_sizes, int n_in,
                              void* d_out, int out_size, void* d_ws, size_t ws_size,
                              hipStream_t stream) {
  const float* x        = (const float*)d_in[0];
  const float* conv0_w  = (const float*)d_in[1];
  const float* conv0_b  = (const float*)d_in[2];
  const float* rconv1_w = (const float*)d_in[3];
  const float* rconv1_b = (const float*)d_in[4];
  const float* rbn1_g   = (const float*)d_in[5];
  const float* rbn1_b   = (const float*)d_in[6];
  const float* rbn1_m   = (const float*)d_in[7];
  const float* rbn1_v   = (const float*)d_in[8];
  const float* rconv2_w = (const float*)d_in[9];
  const float* rconv2_b = (const float*)d_in[10];
  const float* rbn2_g   = (const float*)d_in[11];
  const float* rbn2_b   = (const float*)d_in[12];
  const float* rbn2_m   = (const float*)d_in[13];
  const float* rbn2_v   = (const float*)d_in[14];
  const float* ln0_g    = (const float*)d_in[15];
  const float* ln0_b    = (const float*)d_in[16];
  const float* wproj0   = (const float*)d_in[17];
  const float* w0       = (const float*)d_in[18];
  const float* vc0      = (const float*)d_in[19];
  const float* bias0    = (const float*)d_in[20];
  const float* ln_g     = (const float*)d_in[21];
  const float* ln_b     = (const float*)d_in[22];
  const float* wproj    = (const float*)d_in[23];
  const float* w        = (const float*)d_in[24];
  const float* vc       = (const float*)d_in[25];
  const float* bias     = (const float*)d_in[26];
  const float* cln_g    = (const float*)d_in[27];
  const float* cln_b    = (const float*)d_in[28];
  const float* cls_w    = (const float*)d_in[29];
  float* out = (float*)d_out;

  // Two 128 MiB arenas.
  float* Af = (float*)d_ws;
  float* Bf = Af + 33554432;
  __hip_bfloat16* Ah = (__hip_bfloat16*)Af;
  __hip_bfloat16* Bh = (__hip_bfloat16*)Bf;

  __hip_bfloat16* hA = Ah;                     // NHWC h (A+0..64MB)
  __hip_bfloat16* hB = Bh;                     // NHWC h (B+0..64MB)
  __hip_bfloat16* hC = Ah + 33554432;          // NHWC h (A+64..128MB, conv only)

  __hip_bfloat16* c2   = Bh;                   // 32 MB  [B+0,32)
  __hip_bfloat16* xnc  = Bh + 16777216;        // 32 MB  [B+32,64)
  __hip_bfloat16* xn3  = Bh + 33554432;        // 32 MB  [B+64,96)
  __hip_bfloat16* tmp  = Bh + 50331648;        // 8 MB   [B+96,104)
  __hip_bfloat16* W3p  = Bh + 54525952;        // 4.5 MB [B+104,..) stride 786432
  __hip_bfloat16* W0p  = Bh + 57671680;        // 2 MB   [B+110,112)
  __hip_bfloat16* Wpt3 = Bh + 58720256;        // 1.5 MB [B+112,..)
  float2* csb          = (float2*)(Bh + 59506688);  // 106 KB [B+113.5,..)
  __hip_bfloat16* wt_all = Bh + 59768832;      // 110 KB [B+114,..)
  __hip_bfloat16* Wp0t   = Bh + 60293120;      // 1 MB   [B+115,116)
  __hip_bfloat16* xn0  = Bh;                   // layer0 LN out (64 MB, transient)
  __hip_bfloat16* U    = Ah;                   // <=128 MB
  __hip_bfloat16* Wct  = Ah;                   // 64 KB (end only)

  const float2* csb4 = csb;
  const float2* csb3 = csb + 4096;

  // ---- batched weight preps (hoisted) ----
  wtap_conv6<<<216, 256, 0, stream>>>(rconv1_w, rconv2_w, wt_all);
  wt_perm0<<<2048, 256, 0, stream>>>(wproj0, Wp0t);
  wexp_prep<<<dim3(16, 8, 8), dim3(32, 8), 0, stream>>>(w0, W0p, 4, 0, 0);
  wexp_prep<<<dim3(16, 8, 24), dim3(32, 8), 0, stream>>>(w, W3p, 3,
                                                         786432, 786432);
  wt_bf16<<<dim3(8, 32, 3), dim3(32, 8), 0, stream>>>(wproj, Wpt3, 1024, 256,
                                                      262144, 262144);
  colsb_prep<<<52, 256, 0, stream>>>(bias0, bias, csb);

  // ---- conv stem + fused residual blocks (hA -> hB -> hC -> hA) ----
  conv_stem_nhwc<<<dim3(64, 16), 256, 0, stream>>>(x, conv0_w, conv0_b, hA);
  __hip_bfloat16* rs[4] = {hA, hB, hC, hA};
  for (int i = 0; i < 3; ++i) {
    conv_res_fused<<<dim3(16, 16, 16), 256, 0, stream>>>(rs[i],
        wt_all + (i * 2) * 9216, wt_all + (i * 2 + 1) * 9216,
        rconv1_b + i * 32, rbn1_g + i * 32, rbn1_b + i * 32,
        rbn1_m + i * 32, rbn1_v + i * 32,
        rconv2_b + i * 32, rbn2_g + i * 32, rbn2_b + i * 32,
        rbn2_m + i * 32, rbn2_v + i * 32, rs[i + 1]);
  }

  // ---- SRU layer 0 (k=4, F=2048): gemms -> c-scan -> fused y+LN[0] ----
  ln_nhwc<<<16384, 256, 0, stream>>>(hA, ln0_g, ln0_b, xn0);
  gemm_bf16<<<dim3(2, 128), 256, 0, stream>>>(xn0, Wp0t, tmp, nullptr,
                                              16384, 256, 2048);
  gemm_bf16<<<dim3(32, 128), 256, 0, stream>>>(tmp, W0p, U, csb4,
                                               16384, 4096, 256);
  scan_c<8192><<<256, 128, 0, stream>>>(U, vc0, c2);
  __hip_bfloat16* xnA = xn3;
  __hip_bfloat16* xnB = xnc;
  yln<1><<<16384, 256, 0, stream>>>(c2, U, nullptr, vc0, ln_g, ln_b, xnA);

  // ---- SRU layers 1..3 (k=3 packed, N=3072); final iter fuses cls LN ----
  for (int i = 0; i < 3; ++i) {
    gemm_bf16<<<dim3(2, 128), 256, 0, stream>>>(xnA, Wpt3 + i * 262144, tmp,
                                                nullptr, 16384, 256, 1024);
    gemm_bf16<<<dim3(24, 128), 256, 0, stream>>>(tmp, W3p + i * 786432, U,
                                                 csb3 + i * 3072, 16384, 3072, 256);
    scan_c<6144><<<256, 128, 0, stream>>>(U, vc + i * 2048, c2);
    const float* gg = (i < 2) ? (ln_g + (i + 1) * 1024) : cln_g;
    const float* bb = (i < 2) ? (ln_b + (i + 1) * 1024) : cln_b;
    yln<0><<<16384, 256, 0, stream>>>(c2, U, xnA, vc + i * 2048, gg, bb, xnB);
    __hip_bfloat16* sw = xnA; xnA = xnB; xnB = sw;
  }

  // ---- classifier (skinny MFMA GEMM); xnA == xnc here ----
  wct_prep<<<128, 256, 0, stream>>>(cls_w, Wct);
  cls_gemm<<<256, 256, 0, stream>>>(xnA, Wct, out);
}

// Round 14
// 964.679 us; speedup vs baseline: 1.0689x; 1.0689x over previous
//
#include <hip/hip_runtime.h>
#include <hip/hip_bf16.h>
#include <math.h>

#define DEV __device__ __forceinline__

typedef __attribute__((ext_vector_type(8))) short short8;
typedef __attribute__((ext_vector_type(4))) float floatx4;

DEV float b2f_lo(unsigned u) { return __uint_as_float(u << 16); }
DEV float b2f_hi(unsigned u) { return __uint_as_float(u & 0xffff0000u); }

#if __has_builtin(__builtin_amdgcn_exp2f)
DEV float fexp2_(float x) { return __builtin_amdgcn_exp2f(x); }
#else
DEV float fexp2_(float x) { return exp2f(x); }
#endif
#if __has_builtin(__builtin_amdgcn_rcpf)
DEV float frcp_(float x) { return __builtin_amdgcn_rcpf(x); }
#else
DEV float frcp_(float x) { return 1.f / x; }
#endif

// async global->LDS, 16B per lane; LDS dest = uniform base + lane*16;
// GLOBAL source address is per-lane.
DEV void gl2lds16(const void* g, void* l) {
  __builtin_amdgcn_global_load_lds(
      (const __attribute__((address_space(1))) unsigned int*)g,
      (__attribute__((address_space(3))) unsigned int*)l, 16, 0, 0);
}

union U8 { uint4 u; __hip_bfloat16 h[8]; };

// fragment-layout column swizzle (within 64-col groups):
// store of logical col l lands at phys p = swz(l); phys p holds logical invswz(p)
DEV int swz64(int x)    { return (x & ~63) | ((x & 15) << 2) | ((x >> 4) & 3); }
DEV int invswz64(int x) { return (x & ~63) | ((x & 3) << 4) | ((x >> 2) & 15); }

// ------- conv stem v3: LDS-staged rows; write-buffered epilogue --------------
__global__ __launch_bounds__(256) void conv_stem_nhwc(const float* __restrict__ x,
    const float* __restrict__ w, const float* __restrict__ bias,
    __hip_bfloat16* __restrict__ out) {
  __shared__ float sX[3][2052];
  __shared__ float sW[288];
  __shared__ float sB[32];
  const int tid = threadIdx.x;
  const int f = blockIdx.x, n = blockIdx.y;
  const float* xb = x + (size_t)n * 262144;

  for (int i = tid; i < 1536; i += 256) {
    int r = i >> 9, c4 = i & 511;
    int fi = 2 * f - 1 + r;
    float4 v = {0.f, 0.f, 0.f, 0.f};
    if (fi >= 0 && fi < 128) v = *(const float4*)&xb[fi * 2048 + c4 * 4];
    sX[r][1 + c4 * 4 + 0] = v.x;
    sX[r][1 + c4 * 4 + 1] = v.y;
    sX[r][1 + c4 * 4 + 2] = v.z;
    sX[r][1 + c4 * 4 + 3] = v.w;
  }
  if (tid < 3) { sX[tid][0] = 0.f; sX[tid][2049] = 0.f; }
  for (int i = tid; i < 288; i += 256) sW[i] = w[i];
  if (tid < 32) sB[tid] = bias[tid];
  __syncthreads();

  float xv[4][9];
#pragma unroll
  for (int q = 0; q < 4; ++q) {
    int t = tid + q * 256;
#pragma unroll
    for (int r = 0; r < 3; ++r)
#pragma unroll
      for (int dc = 0; dc < 3; ++dc)
        xv[q][r * 3 + dc] = sX[r][2 * t + dc];
  }

  U8 ores[4][4];  // [ocq][q]
#pragma unroll
  for (int ocq = 0; ocq < 4; ++ocq) {
#pragma unroll
    for (int oo = 0; oo < 8; ++oo) {
      float w9[9];
#pragma unroll
      for (int qq = 0; qq < 9; ++qq) w9[qq] = sW[(ocq * 8 + oo) * 9 + qq];
      float b0 = sB[ocq * 8 + oo];
#pragma unroll
      for (int q = 0; q < 4; ++q) {
        float acc = b0;
#pragma unroll
        for (int qq = 0; qq < 9; ++qq) acc = fmaf(w9[qq], xv[q][qq], acc);
        ores[ocq][q].h[oo] = __float2bfloat16(acc);
      }
    }
  }

#pragma unroll
  for (int q = 0; q < 4; ++q) {
    int t = tid + q * 256;
    uint4* dst = (uint4*)&out[(((size_t)n * 64 + f) * 1024 + t) * 32];
    dst[0] = ores[0][q].u;
    dst[1] = ores[1][q].u;
    dst[2] = ores[2][q].u;
    dst[3] = ores[3][q].u;
  }
}

// ----- batched weight swizzle: 6 conv layers -> [buf][tap][oc][ic] bf16 ------
__global__ __launch_bounds__(256) void wtap_conv6(const float* __restrict__ w1,
    const float* __restrict__ w2, __hip_bfloat16* __restrict__ out) {
  int i = blockIdx.x * 256 + threadIdx.x;        // 0..55295
  if (i < 55296) {
    int b = i / 9216, r = i - b * 9216;
    int layer = b >> 1, which = b & 1;
    const float* src = (which ? w2 : w1) + layer * 9216;
    int tap = r >> 10, oc = (r >> 5) & 31, ic = r & 31;
    out[b * 9216 + r] = __float2bfloat16(src[(oc * 32 + ic) * 9 + tap]);
  }
}

// ------ residual conv 3x3 MFMA v3: 4 f-rows x 64 t per block -----------------
template <int ADD>
__global__ __launch_bounds__(256) void conv_mfma(const __hip_bfloat16* __restrict__ Hin,
    const __hip_bfloat16* __restrict__ wt,
    const float* __restrict__ cb, const float* __restrict__ bg,
    const float* __restrict__ bb, const float* __restrict__ bm,
    const float* __restrict__ bv, __hip_bfloat16* Hres) {
  __shared__ __hip_bfloat16 sIn[6 * 66 * 40];   // 31680 B
  __hip_bfloat16* sOut = sIn;                    // needs 4*64*40 = 10240 elems
  const int tid = threadIdx.x;
  const int tb = blockIdx.x, fb = blockIdx.y, n = blockIdx.z;
  const int t0 = tb * 64, f0 = fb * 4;
  const __hip_bfloat16* Hb = Hin + (size_t)n * 2097152;

  for (int c = tid; c < 1584; c += 256) {
    int rr = c / 264;
    int r2 = c - rr * 264;
    int p = r2 >> 2, icq = r2 & 3;
    int fi = f0 - 1 + rr;
    int tg = t0 + p - 1;
    uint4 v = {0, 0, 0, 0};
    if (fi >= 0 && fi < 64 && tg >= 0 && tg < 1024)
      v = *(const uint4*)&Hb[((size_t)fi * 1024 + tg) * 32 + icq * 8];
    *(uint4*)&sIn[(rr * 66 + p) * 40 + icq * 8] = v;
  }

  const int lane = tid & 63, wave = tid >> 6;
  const int fr = lane & 15, fq = lane >> 4;
  short8 bfrag[9][2];
#pragma unroll
  for (int tap = 0; tap < 9; ++tap)
#pragma unroll
    for (int j = 0; j < 2; ++j)
      bfrag[tap][j] = *(const short8*)&wt[(tap * 32 + j * 16 + fr) * 32 + fq * 8];

  __syncthreads();

  const int tw = wave * 16;
  floatx4 acc[4][2];
#pragma unroll
  for (int fp = 0; fp < 4; ++fp)
#pragma unroll
    for (int j = 0; j < 2; ++j) acc[fp][j] = (floatx4){0.f, 0.f, 0.f, 0.f};

#pragma unroll
  for (int fp = 0; fp < 4; ++fp) {
    int pbase = tw + fr;
#pragma unroll
    for (int df = 0; df < 3; ++df)
#pragma unroll
      for (int dc = 0; dc < 3; ++dc) {
        short8 af =
            *(const short8*)&sIn[((fp + df) * 66 + pbase + dc) * 40 + fq * 8];
        acc[fp][0] = __builtin_amdgcn_mfma_f32_16x16x32_bf16(
            af, bfrag[df * 3 + dc][0], acc[fp][0], 0, 0, 0);
        acc[fp][1] = __builtin_amdgcn_mfma_f32_16x16x32_bf16(
            af, bfrag[df * 3 + dc][1], acc[fp][1], 0, 0, 0);
      }
  }

  float sc0 = bg[fr] * rsqrtf(bv[fr] + 1e-5f);
  float sh0 = (cb[fr] - bm[fr]) * sc0 + bb[fr];
  float sc1 = bg[fr + 16] * rsqrtf(bv[fr + 16] + 1e-5f);
  float sh1 = (cb[fr + 16] - bm[fr + 16]) * sc1 + bb[fr + 16];

  __syncthreads();
#pragma unroll
  for (int fp = 0; fp < 4; ++fp)
#pragma unroll
    for (int j = 0; j < 2; ++j) {
      float sc = j ? sc1 : sc0, sh = j ? sh1 : sh0;
#pragma unroll
      for (int reg = 0; reg < 4; ++reg) {
        int t_l = tw + fq * 4 + reg;
        sOut[(fp * 64 + t_l) * 40 + j * 16 + fr] =
            __float2bfloat16(acc[fp][j][reg] * sc + sh);
      }
    }
  __syncthreads();

  for (int c = tid; c < 1024; c += 256) {
    int fp = c >> 8, rem = c & 255;
    int t_l = rem >> 2, icq = rem & 3;
    U8 y;
    y.u = *(uint4*)&sOut[(fp * 64 + t_l) * 40 + icq * 8];
    size_t addr = (((size_t)n * 64 + f0 + fp) * 1024 + t0 + t_l) * 32 + icq * 8;
    U8 o;
    if (ADD) {
      U8 r;
      r.u = *(const uint4*)&Hres[addr];
#pragma unroll
      for (int i = 0; i < 8; ++i)
        o.h[i] = __float2bfloat16(
            fmaxf(__bfloat162float(y.h[i]) + __bfloat162float(r.h[i]), 0.f));
    } else {
#pragma unroll
      for (int i = 0; i < 8; ++i)
        o.h[i] = __float2bfloat16(fmaxf(__bfloat162float(y.h[i]), 0.f));
    }
    *(uint4*)&Hres[addr] = o.u;
  }
}

// ------ LN over NHWC row (t,n): F=2048, k-order k' = f*32+ic, bf16 out -------
__global__ __launch_bounds__(256) void ln_nhwc(const __hip_bfloat16* __restrict__ H,
    const float* __restrict__ g, const float* __restrict__ b,
    __hip_bfloat16* __restrict__ xn) {
  int r = blockIdx.x;
  int t = r >> 4, n = r & 15;
  int tid = threadIdx.x;
  int f = tid >> 2, icq = tid & 3;
  U8 v;
  v.u = *(const uint4*)&H[(((size_t)n * 64 + f) * 1024 + t) * 32 + icq * 8];
  float xv[8];
  float sum = 0.f, ss = 0.f;
#pragma unroll
  for (int i = 0; i < 8; ++i) {
    xv[i] = __bfloat162float(v.h[i]);
    sum += xv[i];
    ss += xv[i] * xv[i];
  }
#pragma unroll
  for (int off = 32; off > 0; off >>= 1) {
    sum += __shfl_down(sum, off);
    ss  += __shfl_down(ss, off);
  }
  __shared__ float red[8];
  int lane = tid & 63, wave = tid >> 6;
  if (lane == 0) { red[wave] = sum; red[4 + wave] = ss; }
  __syncthreads();
  sum = red[0] + red[1] + red[2] + red[3];
  ss  = red[4] + red[5] + red[6] + red[7];
  float mean = sum * (1.f / 2048.f);
  float var = ss * (1.f / 2048.f) - mean * mean;
  float inv = rsqrtf(var + 1e-5f);
  U8 o;
#pragma unroll
  for (int i = 0; i < 8; ++i) {
    int cf = (icq * 8 + i) * 64 + f;
    o.h[i] = __float2bfloat16((xv[i] - mean) * inv * g[cf] + b[cf]);
  }
  *(uint4*)&xn[(size_t)r * 2048 + tid * 8] = o.u;
}

// -- wproj0 permuted transpose: Wp0t[p][k'=f*32+ic] = wproj0[ic*64+f][p] bf16 --
__global__ __launch_bounds__(256) void wt_perm0(const float* __restrict__ in,
    __hip_bfloat16* __restrict__ out) {
  int i = blockIdx.x * 256 + threadIdx.x;
  int p = i >> 11, kp = i & 2047;
  int ic = kp & 31, f = kp >> 5;
  out[i] = __float2bfloat16(in[(ic * 64 + f) * 256 + p]);
}

// ------- weight convert+transpose (batched over z): (K x N) -> (N x K) bf16 --
__global__ __launch_bounds__(256) void wt_bf16(const float* __restrict__ in,
    __hip_bfloat16* __restrict__ out, int K, int N, int inStride, int outStride) {
  __shared__ float tile[32][33];
  int x = threadIdx.x, y0 = threadIdx.y;
  int bn = blockIdx.x * 32;
  int bk = blockIdx.y * 32;
  const float* src = in + (size_t)blockIdx.z * inStride;
  __hip_bfloat16* dst = out + (size_t)blockIdx.z * outStride;
#pragma unroll
  for (int i = 0; i < 4; ++i) {
    int yy = y0 + i * 8;
    tile[yy][x] = src[(size_t)(bk + yy) * N + bn + x];
  }
  __syncthreads();
#pragma unroll
  for (int i = 0; i < 4; ++i) {
    int yy = y0 + i * 8;
    dst[(size_t)(bn + yy) * K + bk + x] = __float2bfloat16(tile[x][yy]);
  }
}

// ---- expansion weight prep (batched): w (256 x korig*1024) fp32 ->
// ---- PHYSICAL U layout (after the GEMM's fragment-swizzled store) matches
// ---- the historical layout, ch = d*512+j:
// ----   korig==4: plane01 ch*2+{0,1} (a0,a1), plane23 2048+ch*2+{0,1} (a2,rx)
// ----   korig==3: plane01 ch*2+{0,1}, a2 plane 2048+ch
// ---- Bt row index = invswz64(physical col); K-cols swizzled to match the
// ---- proj GEMM's swizzled tmp output. -------------------------------------
__global__ void wexp_prep(const float* __restrict__ in,
    __hip_bfloat16* __restrict__ out, int korig, int inStride, int outStride) {
  __shared__ float tile[32][33];
  int jt = blockIdx.x;
  int ckt = blockIdx.y;
  int z = blockIdx.z;
  int layer = z >> 3, dk = z & 7;
  int d = dk >> 2, k = dk & 3;
  if (k >= korig) return;
  const float* src = in + (size_t)layer * inStride;
  __hip_bfloat16* dst = out + (size_t)layer * outStride;
  int x = threadIdx.x, y0 = threadIdx.y;
#pragma unroll
  for (int i = 0; i < 4; ++i) {
    int yy = y0 + i * 8;
    tile[yy][x] = src[(size_t)(ckt * 32 + yy) * (korig * 1024) +
                      (d * korig + k) * 512 + jt * 32 + x];
  }
  __syncthreads();
#pragma unroll
  for (int i = 0; i < 4; ++i) {
    int yy = y0 + i * 8;
    int ch = d * 512 + jt * 32 + yy;
    int rOld;
    if (korig == 4)
      rOld = (k < 2) ? (ch * 2 + k) : (2048 + ch * 2 + (k - 2));
    else
      rOld = (k < 2) ? (ch * 2 + k) : (2048 + ch);
    int rNew = invswz64(rOld);
    int ckp = swz64(ckt * 32 + x);
    dst[(size_t)rNew * 256 + ckp] = __float2bfloat16(tile[x][yy]);
  }
}

// ---- per-column scale/bias tables (physical col) ---------------------------
__global__ __launch_bounds__(256) void colsb_prep(const float* __restrict__ bias0,
    const float* __restrict__ bias3, float2* __restrict__ out) {
  int i = blockIdx.x * 256 + threadIdx.x;
  if (i >= 13312) return;
  const float NL2E = -1.44269504f;
  float s = 1.f, bb = 0.f;
  if (i < 4096) {
    int col = i;
    if (col < 2048) {
      int ch = col >> 1, e = col & 1;
      int d = ch >> 9, jj = ch & 511;
      if (e) { s = NL2E; bb = NL2E * bias0[d * 1024 + jj]; }
    } else {
      int cc = col - 2048, ch = cc >> 1, e = cc & 1;
      int d = ch >> 9, jj = ch & 511;
      if (!e) { s = NL2E; bb = NL2E * bias0[d * 1024 + 512 + jj]; }
    }
  } else {
    int rem = i - 4096;
    int layer = rem / 3072, col = rem - layer * 3072;
    const float* bsrc = bias3 + layer * 2048;
    if (col < 2048) {
      int ch = col >> 1, e = col & 1;
      int d = ch >> 9, jj = ch & 511;
      if (e) { s = NL2E; bb = NL2E * bsrc[d * 1024 + jj]; }
    } else {
      int ch = col - 2048;
      int d = ch >> 9, jj = ch & 511;
      s = NL2E; bb = NL2E * bsrc[d * 1024 + 512 + jj];
    }
  }
  out[i] = make_float2(s, bb);
}

// ---- cls_w (1024x30) fp32 -> Wct (32x1024) bf16, rows >=30 zero -------------
__global__ __launch_bounds__(256) void wct_prep(const float* __restrict__ in,
    __hip_bfloat16* __restrict__ out) {
  int i = blockIdx.x * 256 + threadIdx.x;
  int nn = i >> 10, kk = i & 1023;
  out[i] = __float2bfloat16(nn < 30 ? in[kk * 30 + nn] : 0.f);
}

// -------- bf16 MFMA GEMM v2: BK=64 double-buffered, counted-vmcnt ------------
__global__ __launch_bounds__(256) void gemm_bf16(const __hip_bfloat16* __restrict__ A,
    const __hip_bfloat16* __restrict__ Bt, __hip_bfloat16* __restrict__ C,
    const float2* __restrict__ csb, int M, int N, int K) {
  __shared__ __hip_bfloat16 As[2][128 * 64];
  __shared__ __hip_bfloat16 Bs[2][128 * 64];
  const int tid = threadIdx.x;
  const int gx = gridDim.x;
  const int nwg = gx * gridDim.y;
  const int bid = blockIdx.y * gx + blockIdx.x;
  const int wgid = (bid & 7) * (nwg >> 3) + (bid >> 3);
  const int m0 = (wgid / gx) * 128, n0 = (wgid % gx) * 128;
  const int lane = tid & 63, wave = tid >> 6;
  const int wm = wave & 1, wn = wave >> 1;
  const int fr = lane & 15, fq = lane >> 4;
  const int frx = fr & 7;

  const int srow8 = lane >> 3;
  const int lslot = (lane & 7) ^ srow8;
  const __hip_bfloat16* gaS = &A[(size_t)(m0 + wave * 32 + srow8) * K + lslot * 8];
  const __hip_bfloat16* gbS = &Bt[(size_t)(n0 + wave * 32 + srow8) * K + lslot * 8];

  floatx4 acc[4][4];
#pragma unroll
  for (int i = 0; i < 4; ++i)
#pragma unroll
    for (int j = 0; j < 4; ++j)
      acc[i][j] = (floatx4){0.f, 0.f, 0.f, 0.f};

#define STAGE(BUF, kk)                                                    \
  {                                                                       \
    _Pragma("unroll") for (int i = 0; i < 4; ++i) {                       \
      gl2lds16(gaS + (size_t)i * 8 * K + (kk),                            \
               &As[BUF][(wave * 32 + i * 8) * 64]);                       \
      gl2lds16(gbS + (size_t)i * 8 * K + (kk),                            \
               &Bs[BUF][(wave * 32 + i * 8) * 64]);                       \
    }                                                                     \
  }
#define COMPUTE(BUF)                                                      \
  {                                                                       \
    _Pragma("unroll") for (int s = 0; s < 2; ++s) {                       \
      const int sl = ((s * 4 + fq) ^ frx) * 8;                            \
      short8 af[4], bf_[4];                                               \
      _Pragma("unroll") for (int i = 0; i < 4; ++i) {                     \
        af[i]  = *(const short8*)&As[BUF][(wm * 64 + i * 16 + fr) * 64 + sl]; \
        bf_[i] = *(const short8*)&Bs[BUF][(wn * 64 + i * 16 + fr) * 64 + sl]; \
      }                                                                   \
      _Pragma("unroll") for (int i = 0; i < 4; ++i)                       \
        _Pragma("unroll") for (int j = 0; j < 4; ++j)                     \
          acc[i][j] = __builtin_amdgcn_mfma_f32_16x16x32_bf16(            \
              af[i], bf_[j], acc[i][j], 0, 0, 0);                         \
    }                                                                     \
  }
#define CFENCE asm volatile("" ::: "memory")

  STAGE(0, 0);
  for (int k0 = 0; k0 < K; k0 += 128) {
    STAGE(1, k0 + 64);
    asm volatile("s_waitcnt vmcnt(8)" ::: "memory");
    __builtin_amdgcn_s_barrier();
    COMPUTE(0);
    CFENCE;
    __builtin_amdgcn_s_barrier();
    if (k0 + 128 < K) {
      STAGE(0, k0 + 128);
      asm volatile("s_waitcnt vmcnt(8)" ::: "memory");
    } else {
      asm volatile("s_waitcnt vmcnt(0)" ::: "memory");
    }
    __builtin_amdgcn_s_barrier();
    COMPUTE(1);
    CFENCE;
    __builtin_amdgcn_s_barrier();
  }
#undef STAGE
#undef COMPUTE
#undef CFENCE

  const int p0 = n0 + wn * 64 + fr * 4;
  float s0 = 1.f, s1 = 1.f, s2 = 1.f, s3 = 1.f;
  float c0 = 0.f, c1 = 0.f, c2v = 0.f, c3 = 0.f;
  if (csb) {
    float2 t0 = csb[p0], t1 = csb[p0 + 1], t2 = csb[p0 + 2], t3 = csb[p0 + 3];
    s0 = t0.x; c0 = t0.y; s1 = t1.x; c1 = t1.y;
    s2 = t2.x; c2v = t2.y; s3 = t3.x; c3 = t3.y;
  }
#pragma unroll
  for (int i = 0; i < 4; ++i)
#pragma unroll
    for (int reg = 0; reg < 4; ++reg) {
      int row = m0 + wm * 64 + i * 16 + fq * 4 + reg;
      union { uint2 u; __hip_bfloat16 h[4]; } o;
      o.h[0] = __float2bfloat16(fmaf(acc[i][0][reg], s0, c0));
      o.h[1] = __float2bfloat16(fmaf(acc[i][1][reg], s1, c1));
      o.h[2] = __float2bfloat16(fmaf(acc[i][2][reg], s2, c2v));
      o.h[3] = __float2bfloat16(fmaf(acc[i][3][reg], s3, c3));
      *(uint2*)&C[(size_t)row * N + p0] = o.u;
    }
}

// ------- skinny classifier GEMM: out[n][t][30] = xnc(16384x1024) @ Wct^T -----
__global__ __launch_bounds__(256) void cls_gemm(const __hip_bfloat16* __restrict__ A,
    const __hip_bfloat16* __restrict__ Wct, float* __restrict__ out) {
  const int tid = threadIdx.x;
  const int lane = tid & 63, wave = tid >> 6;
  const int fr = lane & 15, fq = lane >> 4;
  const int m0 = (blockIdx.x * 4 + wave) * 16;
  floatx4 acc[2];
  acc[0] = (floatx4){0.f, 0.f, 0.f, 0.f};
  acc[1] = (floatx4){0.f, 0.f, 0.f, 0.f};
#pragma unroll 4
  for (int k0 = 0; k0 < 1024; k0 += 32) {
    short8 af = *(const short8*)&A[(size_t)(m0 + fr) * 1024 + k0 + fq * 8];
    short8 b0 = *(const short8*)&Wct[(size_t)fr * 1024 + k0 + fq * 8];
    short8 b1 = *(const short8*)&Wct[(size_t)(16 + fr) * 1024 + k0 + fq * 8];
    acc[0] = __builtin_amdgcn_mfma_f32_16x16x32_bf16(af, b0, acc[0], 0, 0, 0);
    acc[1] = __builtin_amdgcn_mfma_f32_16x16x32_bf16(af, b1, acc[1], 0, 0, 0);
  }
#pragma unroll
  for (int j = 0; j < 2; ++j) {
    int col = j * 16 + fr;
    if (col < 30) {
#pragma unroll
      for (int reg = 0; reg < 4; ++reg) {
        int row = m0 + fq * 4 + reg;
        int t = row >> 4, n = row & 15;
        out[(size_t)n * 30720 + t * 30 + col] = acc[j][reg];
      }
    }
  }
}

// ---------- SRU c-chain (pass 1), producer/consumer LDS pipeline -------------
template <int ROWB>
__global__ __launch_bounds__(128) void scan_c(const __hip_bfloat16* __restrict__ U,
    const float* __restrict__ vc, __hip_bfloat16* __restrict__ c2out) {
  __shared__ uint slab[16 * 1024];   // 16 slots x 4 KB
  const int b = blockIdx.x;
  const int lane = threadIdx.x & 63;
  const int wave = threadIdx.x >> 6;
  const int jb = (b * 64) & 511;          // block's j base
  const int n = (b >> 3) & 15;
  const int d = b >> 7;
  const float NL2E = -1.44269504f;

  const ptrdiff_t US = (ptrdiff_t)16 * ROWB;        // per-t-step byte stride
  const char* stripe0 = (const char*)U + (size_t)n * ROWB + (size_t)(d * 512 + jb) * 4;
  const char* baseDir = d ? stripe0 + 1023 * US : stripe0;
  const ptrdiff_t stepStride = d ? -US : US;

  if (wave == 1) {
    // ---- producer ----
    const int D = 12;
    const int sgrp = lane >> 4;             // step-in-group 0..3
    const int chunk = lane & 15;            // 16B chunk within 256B stripe
#define ISSUE4(BB)                                                        \
    {                                                                     \
      int slot = (BB) & 15;                                               \
      _Pragma("unroll") for (int i = 0; i < 4; ++i) {                     \
        int s = (BB) * 16 + i * 4 + sgrp;                                 \
        const char* src = baseDir + (ptrdiff_t)s * stepStride + chunk * 16; \
        gl2lds16(src, (char*)slab + slot * 4096 + i * 1024);              \
      }                                                                   \
    }
    for (int bb = 0; bb < D; ++bb) ISSUE4(bb);
    for (int bb = 0; bb < 64; ++bb) {
      if (bb + D < 64) {
        ISSUE4(bb + D);
        asm volatile("s_waitcnt vmcnt(48)" ::: "memory");
      } else {
        asm volatile("s_waitcnt vmcnt(0)" ::: "memory");
      }
      __builtin_amdgcn_s_barrier();
    }
#undef ISSUE4
  } else {
    // ---- consumer ----
    const int j = jb + lane;
    float vf2 = NL2E * vc[d * 1024 + j];
    char* Ob = (char*)c2out + (size_t)n * 2048 + (size_t)(d * 512 + j) * 2;
    const int OS = d ? -32768 : 32768;
    int ooff = d ? 1023 * 32768 : 0;
    float c = 0.f;
    for (int bb = 0; bb < 64; ++bb) {
      __builtin_amdgcn_s_barrier();
      asm volatile("" ::: "memory");
      const uint* slot = slab + (bb & 15) * 1024;
#pragma unroll
      for (int ss = 0; ss < 16; ++ss) {
        uint u = slot[ss * 64 + lane];
        float a0 = b2f_lo(u), a1p = b2f_hi(u);
        float f = frcp_(1.f + fexp2_(fmaf(vf2, c, a1p)));
        c = fmaf(f, c - a0, a0);
        *(__hip_bfloat16*)(Ob + ooff) = __float2bfloat16(c);
        ooff += OS;
      }
    }
  }
}

// ---------- fused y = r*c2 + (1-r)*rx  +  LayerNorm over 1024 (pass 2) -------
template <int K4>
__global__ __launch_bounds__(256) void yln(const __hip_bfloat16* __restrict__ c2buf,
    const __hip_bfloat16* __restrict__ U, const __hip_bfloat16* __restrict__ xn,
    const float* __restrict__ vc, const float* __restrict__ g,
    const float* __restrict__ b, __hip_bfloat16* __restrict__ outx) {
  int r = blockIdx.x;
  int tid = threadIdx.x;
  int ch0 = tid * 4;
  const float NL2E = -1.44269504f;

  union { ushort4 u; __hip_bfloat16 h[4]; } cv;
  cv.u = *(const ushort4*)&c2buf[(size_t)r * 1024 + ch0];
  float a2p[4], rx[4];
  if (K4) {
    uint4 pr = *(const uint4*)((const char*)U + (size_t)r * 8192 + 4096 + tid * 16);
    uint pp[4] = {pr.x, pr.y, pr.z, pr.w};
#pragma unroll
    for (int i = 0; i < 4; ++i) { a2p[i] = b2f_lo(pp[i]); rx[i] = b2f_hi(pp[i]); }
  } else {
    union { ushort4 u; __hip_bfloat16 h[4]; } av, xv;
    av.u = *(const ushort4*)((const char*)U + (size_t)r * 6144 + 4096 + tid * 8);
    xv.u = *(const ushort4*)&xn[(size_t)r * 1024 + ch0];
#pragma unroll
    for (int i = 0; i < 4; ++i) {
      a2p[i] = __bfloat162float(av.h[i]);
      rx[i]  = __bfloat162float(xv.h[i]);
    }
  }

  int d = ch0 >> 9, j0 = ch0 & 511;
  float y[4], sum = 0.f, ss = 0.f;
#pragma unroll
  for (int i = 0; i < 4; ++i) {
    float vr2 = NL2E * vc[d * 1024 + 512 + j0 + i];
    float cc = __bfloat162float(cv.h[i]);
    float rr = frcp_(1.f + fexp2_(fmaf(vr2, cc, a2p[i])));
    y[i] = fmaf(rr, cc - rx[i], rx[i]);
    sum += y[i];
    ss += y[i] * y[i];
  }
#pragma unroll
  for (int off = 32; off > 0; off >>= 1) {
    sum += __shfl_down(sum, off);
    ss  += __shfl_down(ss, off);
  }
  __shared__ float red[8];
  int lane = tid & 63, wave = tid >> 6;
  if (lane == 0) { red[wave] = sum; red[4 + wave] = ss; }
  __syncthreads();
  sum = red[0] + red[1] + red[2] + red[3];
  ss  = red[4] + red[5] + red[6] + red[7];
  float mean = sum * (1.f / 1024.f);
  float var = ss * (1.f / 1024.f) - mean * mean;
  float inv = rsqrtf(var + 1e-5f);
  float4 gv = *(const float4*)&g[ch0];
  float4 bv = *(const float4*)&b[ch0];
  float gg[4] = {gv.x, gv.y, gv.z, gv.w};
  float bb[4] = {bv.x, bv.y, bv.z, bv.w};
  union { ushort4 u; __hip_bfloat16 h[4]; } o;
#pragma unroll
  for (int i = 0; i < 4; ++i)
    o.h[i] = __float2bfloat16((y[i] - mean) * inv * gg[i] + bb[i]);
  *(ushort4*)&outx[(size_t)r * 1024 + ch0] = o.u;
}

extern "C" void kernel_launch(void* const* d_in, const int* in_sizes, int n_in,
                              void* d_out, int out_size, void* d_ws, size_t ws_size,
                              hipStream_t stream) {
  const float* x        = (const float*)d_in[0];
  const float* conv0_w  = (const float*)d_in[1];
  const float* conv0_b  = (const float*)d_in[2];
  const float* rconv1_w = (const float*)d_in[3];
  const float* rconv1_b = (const float*)d_in[4];
  const float* rbn1_g   = (const float*)d_in[5];
  const float* rbn1_b   = (const float*)d_in[6];
  const float* rbn1_m   = (const float*)d_in[7];
  const float* rbn1_v   = (const float*)d_in[8];
  const float* rconv2_w = (const float*)d_in[9];
  const float* rconv2_b = (const float*)d_in[10];
  const float* rbn2_g   = (const float*)d_in[11];
  const float* rbn2_b   = (const float*)d_in[12];
  const float* rbn2_m   = (const float*)d_in[13];
  const float* rbn2_v   = (const float*)d_in[14];
  const float* ln0_g    = (const float*)d_in[15];
  const float* ln0_b    = (const float*)d_in[16];
  const float* wproj0   = (const float*)d_in[17];
  const float* w0       = (const float*)d_in[18];
  const float* vc0      = (const float*)d_in[19];
  const float* bias0    = (const float*)d_in[20];
  const float* ln_g     = (const float*)d_in[21];
  const float* ln_b     = (const float*)d_in[22];
  const float* wproj    = (const float*)d_in[23];
  const float* w        = (const float*)d_in[24];
  const float* vc       = (const float*)d_in[25];
  const float* bias     = (const float*)d_in[26];
  const float* cln_g    = (const float*)d_in[27];
  const float* cln_b    = (const float*)d_in[28];
  const float* cls_w    = (const float*)d_in[29];
  float* out = (float*)d_out;

  // Two 128 MiB arenas.
  float* Af = (float*)d_ws;
  float* Bf = Af + 33554432;
  __hip_bfloat16* Ah = (__hip_bfloat16*)Af;
  __hip_bfloat16* Bh = (__hip_bfloat16*)Bf;

  __hip_bfloat16* hA     = Ah;                 // NHWC h (64 MB)
  __hip_bfloat16* hB     = Bh;                 // NHWC temp
  __hip_bfloat16* wt_all = Ah + 62914560;      // 6 x 18 KB @ A+120MB
  __hip_bfloat16* Wp0t   = Ah + 52428800;      // 1 MB @ A+100MB

  __hip_bfloat16* c2   = Bh;                   // 32 MB  [B+0,32)
  __hip_bfloat16* xnc  = Bh + 16777216;        // 32 MB  [B+32,64)
  __hip_bfloat16* xn3  = Bh + 33554432;        // 32 MB  [B+64,96)
  __hip_bfloat16* tmp  = Bh + 50331648;        // 8 MB   [B+96,104)
  __hip_bfloat16* W3p  = Bh + 54525952;        // 4.5 MB [B+104,..) stride 786432
  __hip_bfloat16* W0p  = Bh + 57671680;        // 2 MB   [B+110,112)
  __hip_bfloat16* Wpt3 = Bh + 58720256;        // 1.5 MB [B+112,..)
  float2* csb          = (float2*)(Bh + 59506688);  // 106 KB [B+113.5,..)
  __hip_bfloat16* xn0  = Bh;                   // layer0 LN out (64 MB, transient)
  __hip_bfloat16* U    = Ah;                   // <=128 MB
  __hip_bfloat16* Wct  = Ah;                   // 64 KB (end only)

  const float2* csb4 = csb;
  const float2* csb3 = csb + 4096;

  // ---- batched weight preps (hoisted) ----
  wtap_conv6<<<216, 256, 0, stream>>>(rconv1_w, rconv2_w, wt_all);
  wt_perm0<<<2048, 256, 0, stream>>>(wproj0, Wp0t);
  wexp_prep<<<dim3(16, 8, 8), dim3(32, 8), 0, stream>>>(w0, W0p, 4, 0, 0);
  wexp_prep<<<dim3(16, 8, 24), dim3(32, 8), 0, stream>>>(w, W3p, 3,
                                                         786432, 786432);
  wt_bf16<<<dim3(8, 32, 3), dim3(32, 8), 0, stream>>>(wproj, Wpt3, 1024, 256,
                                                      262144, 262144);
  colsb_prep<<<52, 256, 0, stream>>>(bias0, bias, csb);

  // ---- conv stem + residual blocks ----
  conv_stem_nhwc<<<dim3(64, 16), 256, 0, stream>>>(x, conv0_w, conv0_b, hA);
  for (int i = 0; i < 3; ++i) {
    conv_mfma<0><<<dim3(16, 16, 16), 256, 0, stream>>>(hA, wt_all + (i * 2) * 9216,
        rconv1_b + i * 32, rbn1_g + i * 32, rbn1_b + i * 32,
        rbn1_m + i * 32, rbn1_v + i * 32, hB);
    conv_mfma<1><<<dim3(16, 16, 16), 256, 0, stream>>>(hB, wt_all + (i * 2 + 1) * 9216,
        rconv2_b + i * 32, rbn2_g + i * 32, rbn2_b + i * 32,
        rbn2_m + i * 32, rbn2_v + i * 32, hA);
  }

  // ---- SRU layer 0 (k=4, F=2048): gemms -> c-scan -> fused y+LN[0] ----
  ln_nhwc<<<16384, 256, 0, stream>>>(hA, ln0_g, ln0_b, xn0);
  gemm_bf16<<<dim3(2, 128), 256, 0, stream>>>(xn0, Wp0t, tmp, nullptr,
                                              16384, 256, 2048);
  gemm_bf16<<<dim3(32, 128), 256, 0, stream>>>(tmp, W0p, U, csb4,
                                               16384, 4096, 256);
  scan_c<8192><<<256, 128, 0, stream>>>(U, vc0, c2);
  __hip_bfloat16* xnA = xn3;
  __hip_bfloat16* xnB = xnc;
  yln<1><<<16384, 256, 0, stream>>>(c2, U, nullptr, vc0, ln_g, ln_b, xnA);

  // ---- SRU layers 1..3 (k=3 packed, N=3072); final iter fuses cls LN ----
  for (int i = 0; i < 3; ++i) {
    gemm_bf16<<<dim3(2, 128), 256, 0, stream>>>(xnA, Wpt3 + i * 262144, tmp,
                                                nullptr, 16384, 256, 1024);
    gemm_bf16<<<dim3(24, 128), 256, 0, stream>>>(tmp, W3p + i * 786432, U,
                                                 csb3 + i * 3072, 16384, 3072, 256);
    scan_c<6144><<<256, 128, 0, stream>>>(U, vc + i * 2048, c2);
    const float* gg = (i < 2) ? (ln_g + (i + 1) * 1024) : cln_g;
    const float* bb = (i < 2) ? (ln_b + (i + 1) * 1024) : cln_b;
    yln<0><<<16384, 256, 0, stream>>>(c2, U, xnA, vc + i * 2048, gg, bb, xnB);
    __hip_bfloat16* sw = xnA; xnA = xnB; xnB = sw;
  }

  // ---- classifier (skinny MFMA GEMM); xnA == xnc here ----
  wct_prep<<<128, 256, 0, stream>>>(cls_w, Wct);
  cls_gemm<<<256, 256, 0, stream>>>(xnA, Wct, out);
}